// Round 13
// baseline (93.960 us; speedup 1.0000x reference)
//
#include <hip/hip_runtime.h>
#include <math.h>

typedef __attribute__((ext_vector_type(8))) short s16x8;
typedef __attribute__((ext_vector_type(4))) float f32x4;

#define N_ROWS 2048
#define D_DIM  128
#define N_CLS  100000
#define N_TILES 782              // ceil(100000/128)
#define N_PAD   96.0f            // 782*128 - 100000 pad classes, each contributes exp2(0)=1
#define S_SCALE 64.0f
#define S_LOG2E 92.33248261689366f   // 64 * log2(e)
#define EPS_F   1e-7f
#define COS_M   0.8775825618903728f  // cos(0.5)
#define SIN_M   0.479425538604203f   // sin(0.5)

#if __has_builtin(__builtin_amdgcn_exp2f)
#define EXP2F(x) __builtin_amdgcn_exp2f(x)
#else
#define EXP2F(x) exp2f(x)
#endif

__device__ __forceinline__ unsigned int f2bf1(float f) {
    unsigned int u = __float_as_uint(f);
    return (u + 0x7FFFu + ((u >> 16) & 1u)) >> 16;   // RNE
}
__device__ __forceinline__ unsigned int f2bf2(float lo, float hi) {
    return f2bf1(lo) | (f2bf1(hi) << 16);
}

// Kernel 1: L2-normalize rows of x -> bf16 in MFMA-B-fragment order, PRESCALED by
// S*log2(e). Fused target logit tgt[i]. 8 threads/row, 32 rows/block (64 blocks).
__global__ __launch_bounds__(256)
void k_normalize(const float* __restrict__ x, const float* __restrict__ W,
                 const int* __restrict__ labels,
                 float* __restrict__ tgt, uint4* __restrict__ xb2) {
    const int t = threadIdx.x;
    const int row = blockIdx.x * 32 + (t >> 3);
    const int p = t & 7;              // 8 threads per row, 16 floats each

    const f32x4* src = (const f32x4*)(x + (size_t)row * D_DIM + p * 16);
    f32x4 v[4];
    float s = 0.f;
    #pragma unroll
    for (int q = 0; q < 4; q++) {
        v[q] = src[q];
        s += v[q][0]*v[q][0] + v[q][1]*v[q][1] + v[q][2]*v[q][2] + v[q][3]*v[q][3];
    }
    s += __shfl_xor(s, 1); s += __shfl_xor(s, 2); s += __shfl_xor(s, 4);
    const float inv = 1.0f / sqrtf(s);

    // fused target-logit dot with W[y] (unscaled, fp32)
    const int y = labels[row];
    const f32x4* wsrc = (const f32x4*)(W + (size_t)y * D_DIM + p * 16);
    float d = 0.f;
    #pragma unroll
    for (int q = 0; q < 4; q++) {
        f32x4 w = wsrc[q];
        d += v[q][0]*w[0] + v[q][1]*w[1] + v[q][2]*w[2] + v[q][3]*w[3];
    }
    d += __shfl_xor(d, 1); d += __shfl_xor(d, 2); d += __shfl_xor(d, 4);
    if (p == 0) tgt[row] = d * inv;

    const float invs = inv * S_LOG2E;  // prescale for the exp2 path
    #pragma unroll
    for (int q = 0; q < 4; q++) {
        v[q][0] *= invs; v[q][1] *= invs; v[q][2] *= invs; v[q][3] *= invs;
    }

    const int gt = row >> 7, rr = row & 127;
    const int wn = rr >> 6, j = (rr >> 4) & 3, lrr = rr & 15;
    #pragma unroll
    for (int c2 = 0; c2 < 2; c2++) {
        const int ck = p * 2 + c2;
        const int ks = ck >> 2, lk = ck & 3;
        const int idx = gt * 2048 + wn * 1024 + j * 256 + ks * 64 + lk * 16 + lrr;
        f32x4 f0 = v[c2 * 2], f1 = v[c2 * 2 + 1];
        xb2[idx] = make_uint4(f2bf2(f0[0], f0[1]), f2bf2(f0[2], f0[3]),
                              f2bf2(f1[0], f1[1]), f2bf2(f1[2], f1[3]));
    }
}

// Kernel 2: one block per 128-class tile; 32 row-tile iterations of 64 rows.
// Per-wave tile = 64 classes x 32 rows -> acc 32 AGPR + a 32 + b-dbuf 32 regs,
// fits the 128-reg budget of 4 waves/SIMD. launch_bounds(256,4) + 40KB LDS =>
// 4 blocks/CU, 16 waves/CU, all 782 blocks co-resident.
__global__ __launch_bounds__(256, 4)
void k_main(const uint4* __restrict__ xb2, const float* __restrict__ W,
            float* __restrict__ rowsum) {
    __shared__ uint4 Wsh[2048];         // 32 KB, fragment-ordered bf16 W tile
    __shared__ float psum[32][64];      // 8 KB: [it][row-in-tile]
    const int t = threadIdx.x;
    const int c0 = blockIdx.x * 128;    // class tile base

    // zero psum (visibility covered by the staging barrier below)
    #pragma unroll
    for (int k = 0; k < 8; k++) ((float*)psum)[t + k * 256] = 0.f;

    // ---- stage + convert W tile, fragment order (once per block) ----
    #pragma unroll
    for (int m = 0; m < 8; m++) {
        const int idx = m * 256 + t;
        const int flr = idx & 15, lk = (idx >> 4) & 3;
        const int ks = (idx >> 6) & 3, fi = (idx >> 8) & 3, fwm = idx >> 10;
        const int cls = c0 + fwm * 64 + fi * 16 + flr;
        const int k0 = (ks * 4 + lk) * 8;
        uint4 val = make_uint4(0u, 0u, 0u, 0u);
        if (cls < N_CLS) {
            const f32x4* g = (const f32x4*)(W + (size_t)cls * D_DIM + k0);
            f32x4 f0 = g[0], f1 = g[1];
            val.x = f2bf2(f0[0], f0[1]); val.y = f2bf2(f0[2], f0[3]);
            val.z = f2bf2(f1[0], f1[1]); val.w = f2bf2(f1[2], f1[3]);
        }
        Wsh[idx] = val;
    }
    __syncthreads();

    const int lane = t & 63;
    const int wid = t >> 6;
    const int wm = wid >> 1;            // class half (0/1)
    const int rh = wid & 1;             // row half within the 64-row tile (0/1)
    const int lr = lane & 15;
    const uint4* bbase = xb2 + rh * 512 + lane;

    uint4 bE[4], bO[4];                 // [jj*2 + ks-within-pair]
    s16x8 a_[2][4];                     // [ks-within-pair][i], reloaded per ks-phase

    // B prologue: ks-pair 0 of it=0
    #pragma unroll
    for (int jj = 0; jj < 2; jj++)
        #pragma unroll
        for (int ks = 0; ks < 2; ks++)
            bE[jj * 2 + ks] = bbase[jj * 256 + ks * 64];

    for (int it = 0; it < 32; it++) {
        f32x4 acc[4][2];                // [i][jj], static indices only
        #pragma unroll
        for (int i = 0; i < 4; i++)
            #pragma unroll
            for (int jj = 0; jj < 2; jj++)
                acc[i][jj] = (f32x4){0.f, 0.f, 0.f, 0.f};

        // ---- ks-phase 0 (ks = 0,1) ----
        // prefetch ks-phase 1's B fragments first (they drain under the MFMAs)
        #pragma unroll
        for (int jj = 0; jj < 2; jj++)
            #pragma unroll
            for (int ks = 0; ks < 2; ks++)
                bO[jj * 2 + ks] = bbase[it * 1024 + jj * 256 + (ks + 2) * 64];
        #pragma unroll
        for (int ks = 0; ks < 2; ks++)
            #pragma unroll
            for (int i = 0; i < 4; i++)
                a_[ks][i] = *(const s16x8*)&Wsh[wm * 1024 + i * 256 + ks * 64 + lane];
        #pragma unroll
        for (int ks = 0; ks < 2; ks++)
            #pragma unroll
            for (int i = 0; i < 4; i++)
                #pragma unroll
                for (int jj = 0; jj < 2; jj++)
                    acc[i][jj] = __builtin_amdgcn_mfma_f32_16x16x32_bf16(
                        a_[ks][i], *(const s16x8*)&bE[jj * 2 + ks], acc[i][jj], 0, 0, 0);

        // ---- ks-phase 1 (ks = 2,3) ----
        if (it < 31) {
            #pragma unroll
            for (int jj = 0; jj < 2; jj++)
                #pragma unroll
                for (int ks = 0; ks < 2; ks++)
                    bE[jj * 2 + ks] = bbase[(it + 1) * 1024 + jj * 256 + ks * 64];
        }
        #pragma unroll
        for (int ks = 0; ks < 2; ks++)
            #pragma unroll
            for (int i = 0; i < 4; i++)
                a_[ks][i] = *(const s16x8*)&Wsh[wm * 1024 + i * 256 + (ks + 2) * 64 + lane];
        #pragma unroll
        for (int ks = 0; ks < 2; ks++)
            #pragma unroll
            for (int i = 0; i < 4; i++)
                #pragma unroll
                for (int jj = 0; jj < 2; jj++)
                    acc[i][jj] = __builtin_amdgcn_mfma_f32_16x16x32_bf16(
                        a_[ks][i], *(const s16x8*)&bO[jj * 2 + ks], acc[i][jj], 0, 0, 0);

        // ---- epilogue: 32 exps, 4 shfls, fire-and-forget LDS atomics ----
        #pragma unroll
        for (int jj = 0; jj < 2; jj++) {
            f32x4 pv;
            #pragma unroll
            for (int r = 0; r < 4; r++)
                pv[r] = (EXP2F(acc[0][jj][r]) + EXP2F(acc[1][jj][r]))
                      + (EXP2F(acc[2][jj][r]) + EXP2F(acc[3][jj][r]));
            float pj = (pv[0] + pv[1]) + (pv[2] + pv[3]);
            pj += __shfl_xor(pj, 16);
            pj += __shfl_xor(pj, 32);
            if ((lane >> 4) == 0)
                atomicAdd(&psum[it][rh * 32 + jj * 16 + lr], pj);
        }
    }

    // ---- one global-atomic burst per block, after all compute ----
    __syncthreads();
    #pragma unroll
    for (int k = 0; k < 8; k++) {
        const int flat = t + k * 256;
        atomicAdd(&rowsum[flat], ((const float*)psum)[flat]);
    }
}

// Kernel 3: per-row loss + mean. Single block. Subtracts the 96 pad-class exps.
__global__ void k_final(const float* __restrict__ rowsum, const float* __restrict__ tgt,
                        float* __restrict__ out) {
    int t = threadIdx.x;
    float lsum = 0.f;
    for (int i = t; i < N_ROWS; i += 256) {
        float tr = tgt[i];
        float tc = fminf(fmaxf(tr, -1.f + EPS_F), 1.f - EPS_F);
        float num = S_SCALE * (tc * COS_M - sqrtf(fmaxf(1.f - tc * tc, 0.f)) * SIN_M);
        float excl = rowsum[i] - N_PAD - __expf(S_SCALE * tr);
        float den = __expf(num) + excl;
        lsum += num - logf(den);
    }
    #pragma unroll
    for (int off = 1; off < 64; off <<= 1) lsum += __shfl_xor(lsum, off);
    __shared__ float wsums[4];
    if ((t & 63) == 0) wsums[t >> 6] = lsum;
    __syncthreads();
    if (t == 0) out[0] = -(wsums[0] + wsums[1] + wsums[2] + wsums[3]) / (float)N_ROWS;
}

extern "C" void kernel_launch(void* const* d_in, const int* in_sizes, int n_in,
                              void* d_out, int out_size, void* d_ws, size_t ws_size,
                              hipStream_t stream) {
    const float* x = (const float*)d_in[0];
    const float* W = (const float*)d_in[1];
    const int* labels = (const int*)d_in[2];
    float* out = (float*)d_out;

    uint4* xb2    = (uint4*)d_ws;                                   // N*D bf16, fragment order
    float* rowsum = (float*)((char*)xb2 + (size_t)N_ROWS * D_DIM * 2);
    float* tgt    = rowsum + N_ROWS;

    hipMemsetAsync(rowsum, 0, N_ROWS * sizeof(float), stream);
    k_normalize<<<N_ROWS / 32, 256, 0, stream>>>(x, W, labels, tgt, xb2);
    k_main<<<N_TILES, 256, 0, stream>>>(xb2, W, rowsum);
    k_final<<<1, 256, 0, stream>>>(rowsum, tgt, out);
}